// Round 8
// baseline (133.298 us; speedup 1.0000x reference)
//
#include <hip/hip_runtime.h>
#include <hip/hip_bf16.h>

// Attention_6828998000803 on MI355X (gfx950)
// H=W=64, C=128, HEADS=4, DIM_HEAD=32, HW=4096, SCALE=10, EPS=1e-8
//
// qkv GEMM (zeroes O/denom, writes Q,K,V^T bf16 + per-block sumsq partials)
// -> flash attention (linear softmax; each wave: ALL 64 q-rows x its own
//    disjoint 256-key stripe; barrier-free main loop; atomicAdd combine)
// -> output projection (divide by denom, bf16 MFMA, + bias)

typedef float  f32x4 __attribute__((ext_vector_type(4)));
typedef short  s16x8 __attribute__((ext_vector_type(8)));
typedef unsigned short u16x4 __attribute__((ext_vector_type(4)));
typedef unsigned short u16;

__device__ __forceinline__ u16 f2bf(float f) {
  unsigned int u = __float_as_uint(f);
  u += 0x7FFFu + ((u >> 16) & 1u);   // round-to-nearest-even
  return (u16)(u >> 16);
}
__device__ __forceinline__ float bf2f(u16 u) {
  return __uint_as_float(((unsigned int)u) << 16);
}
__device__ __forceinline__ s16x8 load8f_bf16(const float* p) {
  const f32x4* q = (const f32x4*)p;
  f32x4 a = q[0], b = q[1];
  s16x8 r;
  r[0]=(short)f2bf(a[0]); r[1]=(short)f2bf(a[1]); r[2]=(short)f2bf(a[2]); r[3]=(short)f2bf(a[3]);
  r[4]=(short)f2bf(b[0]); r[5]=(short)f2bf(b[1]); r[6]=(short)f2bf(b[2]); r[7]=(short)f2bf(b[3]);
  return r;
}

// ---------------------------------------------------------------------------
// K1: qkv = x @ w_in^T  (M=4096, K=128, N=384), grid (128 Mtiles of 32, 3 g)
// 256 thr = 4 waves: wave (wm,wn) does rows wm*16..+16, cols wn*64..+64.
// Also zeroes Oat+denom (grid-stride) so no separate memset dispatch.
// ---------------------------------------------------------------------------
__global__ __launch_bounds__(256) void qkv_kernel(
    const float* __restrict__ x, const float* __restrict__ w_in,
    u16* __restrict__ Qb, u16* __restrict__ Kb, u16* __restrict__ Vtb,
    float* __restrict__ part_sq, float* __restrict__ zbase) {
  const int tid = threadIdx.x;
  // --- zero O/denom accumulators: 135168 f32x4 across 98304 threads
  {
    int gtid = (blockIdx.y * gridDim.x + blockIdx.x) * 256 + tid;
    f32x4 z = {0.f, 0.f, 0.f, 0.f};
    for (int idx = gtid; idx < 135168; idx += 98304) ((f32x4*)zbase)[idx] = z;
  }
  __shared__ float sqpart[2][128];
  const int w = tid >> 6, lane = tid & 63, li = lane & 15, kg = lane >> 4;
  const int wm = w & 1, wn = w >> 1;
  const int g = blockIdx.y;
  const int mb = blockIdx.x;
  const int irow = mb * 32 + wm * 16;

  s16x8 ax[4];
#pragma unroll
  for (int kc = 0; kc < 4; ++kc)
    ax[kc] = load8f_bf16(x + (size_t)(irow + li) * 128 + kc * 32 + kg * 8);

  const float* W = w_in + (size_t)g * 128 * 128;
#pragma unroll
  for (int nt = 0; nt < 4; ++nt) {
    const int colrel = wn * 64 + nt * 16 + li;
    f32x4 acc = {0.f, 0.f, 0.f, 0.f};
#pragma unroll
    for (int kc = 0; kc < 4; ++kc) {
      s16x8 bw = load8f_bf16(W + (size_t)colrel * 128 + kc * 32 + kg * 8);
      acc = __builtin_amdgcn_mfma_f32_16x16x32_bf16(ax[kc], bw, acc, 0, 0, 0);
    }
    const int h = colrel >> 5, d = colrel & 31;
    const int r0 = irow + kg * 4;
    if (g == 2) {
      u16x4 pv;
#pragma unroll
      for (int r = 0; r < 4; ++r) pv[r] = f2bf(acc[r]);
      *(u16x4*)(Vtb + ((size_t)(h * 32 + d) * 4096 + r0)) = pv;   // V^T[h][d][i]
    } else {
      float ss = acc[0]*acc[0] + acc[1]*acc[1] + acc[2]*acc[2] + acc[3]*acc[3];
      ss += __shfl_xor(ss, 16);
      ss += __shfl_xor(ss, 32);            // sum over this wave's 16 rows
      if (lane < 16) sqpart[wm][colrel] = ss;
      u16* dst = (g == 0 ? Qb : Kb);
#pragma unroll
      for (int r = 0; r < 4; ++r)
        dst[((size_t)h * 4096 + r0 + r) * 32 + d] = f2bf(acc[r]);
    }
  }
  __syncthreads();
  if (g < 2 && tid < 128)
    part_sq[((size_t)g * 128 + tid) * 128 + mb] = sqpart[0][tid] + sqpart[1][tid];
}

// ---------------------------------------------------------------------------
// K2: flash attention, linear softmax (|sim| <= ~1.3, no max tracking).
// grid (64 q-blocks of 64 rows, 4 heads, 4 chunks), 4 waves/block.
// Each wave: ALL 64 q-rows (4 Q fragments) x its own DISJOINT 256-key stripe
// (jbase = s*1024 + w*256).  Coverage: union over (s,w) = all 4096 keys per
// q-row.  Partials additive (linear softmax) -> atomicAdd combine.
// Barrier-free main loop; register prefetch; per-wave swizzled P slab.
// ---------------------------------------------------------------------------
__global__ __launch_bounds__(256, 2) void attn_kernel(
    const u16* __restrict__ Qb, const u16* __restrict__ Kb,
    const u16* __restrict__ Vtb, const float* __restrict__ part_sq,
    float* __restrict__ Oat, float* __restrict__ denom) {
  __shared__ float scs[32];
  __shared__ __align__(16) u16 Plds[4][16][64];   // per-wave P[i][j], 128B rows
  const int tid = threadIdx.x;
  const int w = tid >> 6, lane = tid & 63, li = lane & 15, kg = lane >> 4;
  const int h = blockIdx.y;
  const int q0 = blockIdx.x * 64;
  const int s  = blockIdx.z;

  // --- prologue: reduce per-Mblock sumsq partials -> scale table (wave 0)
  if (w == 0) {
    const int kind = lane >> 5, d = lane & 31;
    const f32x4* p4 = (const f32x4*)(part_sq + (size_t)(kind * 128 + h * 32 + d) * 128);
    float sum = 0.f;
#pragma unroll
    for (int m = 0; m < 32; ++m) { f32x4 v = p4[m]; sum += (v[0]+v[1]) + (v[2]+v[3]); }
    float n = fmaxf(sqrtf(sum), 1e-8f);
    float other = __shfl_xor(n, 32);         // pair q-norm with k-norm, same d
    if (lane < 32) scs[lane] = 10.f / (n * other);
  }
  __syncthreads();

  // --- 4 Q fragments: q-group qg covers rows q0+qg*16 .. +16, scale folded
  s16x8 aq[4];
#pragma unroll
  for (int qg = 0; qg < 4; ++qg) {
    const u16* qp = Qb + ((size_t)h * 4096 + q0 + qg * 16 + li) * 32 + kg * 8;
    s16x8 qr = *(const s16x8*)qp;
    s16x8 t;
#pragma unroll
    for (int e = 0; e < 8; ++e) t[e] = (short)f2bf(bf2f((u16)qr[e]) * scs[kg * 8 + e]);
    aq[qg] = t;
  }

  const u16* Kh = Kb  + (size_t)h * 4096 * 32;
  const u16* Vh = Vtb + (size_t)h * 32 * 4096;
  char* Pw = (char*)&Plds[w][0][0];
  const int pbase = li * 128;
  const int psw   = (li & 7) << 4;           // XOR bank swizzle

  f32x4 acc[4][2];
#pragma unroll
  for (int qg = 0; qg < 4; ++qg) { acc[qg][0] = (f32x4){0,0,0,0}; acc[qg][1] = (f32x4){0,0,0,0}; }
  float sden[4] = {0.f, 0.f, 0.f, 0.f};
  const int jbase = s * 1024 + w * 256;      // this wave's private key stripe

  // preload stripe-tile 0
  s16x8 kf[4], vf[4];
#pragma unroll
  for (int jb = 0; jb < 4; ++jb)
    kf[jb] = *(const s16x8*)(Kh + (size_t)(jbase + jb * 16 + li) * 32 + kg * 8);
#pragma unroll
  for (int c = 0; c < 2; ++c)
#pragma unroll
    for (int hf = 0; hf < 2; ++hf)
      vf[c * 2 + hf] = *(const s16x8*)(Vh + (size_t)(li + hf * 16) * 4096 + jbase + c * 32 + kg * 8);

#pragma unroll
  for (int it = 0; it < 4; ++it) {
    // prefetch next 64-key tile of this wave's stripe
    s16x8 kn[4], vn[4];
    if (it < 3) {
      const int j1 = jbase + (it + 1) * 64;
#pragma unroll
      for (int jb = 0; jb < 4; ++jb)
        kn[jb] = *(const s16x8*)(Kh + (size_t)(j1 + jb * 16 + li) * 32 + kg * 8);
#pragma unroll
      for (int c = 0; c < 2; ++c)
#pragma unroll
        for (int hf = 0; hf < 2; ++hf)
          vn[c * 2 + hf] = *(const s16x8*)(Vh + (size_t)(li + hf * 16) * 4096 + j1 + c * 32 + kg * 8);
    }

    // 4 independent q-group chains over this 64-key tile
#pragma unroll
    for (int qg = 0; qg < 4; ++qg) {
      // S^T = K Q^T : lane holds S[j = jb*16 + kg*4 + r][q = li]
      f32x4 st[4];
      __builtin_amdgcn_s_setprio(1);
#pragma unroll
      for (int jb = 0; jb < 4; ++jb) {
        f32x4 z = {0, 0, 0, 0};
        st[jb] = __builtin_amdgcn_mfma_f32_16x16x32_bf16(kf[jb], aq[qg], z, 0, 0, 0);
      }
      __builtin_amdgcn_s_setprio(0);
      // exp (no max), denominator accumulate, pack P -> LDS (b64, swizzled)
#pragma unroll
      for (int jb = 0; jb < 4; ++jb) {
        float p0 = __expf(st[jb][0]), p1 = __expf(st[jb][1]);
        float p2 = __expf(st[jb][2]), p3 = __expf(st[jb][3]);
        sden[qg] += (p0 + p1) + (p2 + p3);
        uint2 pk;
        pk.x = (unsigned)f2bf(p0) | ((unsigned)f2bf(p1) << 16);
        pk.y = (unsigned)f2bf(p2) | ((unsigned)f2bf(p3) << 16);
        *(uint2*)(Pw + pbase + ((jb * 32 + kg * 8) ^ psw)) = pk;
      }
      // O += P V  (wave-internal LDS round-trip, no barrier)
#pragma unroll
      for (int c = 0; c < 2; ++c) {
        s16x8 ap = *(const s16x8*)(Pw + pbase + ((c * 64 + kg * 16) ^ psw));
        __builtin_amdgcn_s_setprio(1);
        acc[qg][0] = __builtin_amdgcn_mfma_f32_16x16x32_bf16(ap, vf[c * 2 + 0], acc[qg][0], 0, 0, 0);
        acc[qg][1] = __builtin_amdgcn_mfma_f32_16x16x32_bf16(ap, vf[c * 2 + 1], acc[qg][1], 0, 0, 0);
        __builtin_amdgcn_s_setprio(0);
      }
    }
    if (it < 3) {
#pragma unroll
      for (int jb = 0; jb < 4; ++jb) kf[jb] = kn[jb];
#pragma unroll
      for (int c = 0; c < 4; ++c) vf[c] = vn[c];
    }
  }

  // --- combine: O and denom are additive across chunks & stripes
#pragma unroll
  for (int qg = 0; qg < 4; ++qg) {
#pragma unroll
    for (int r = 0; r < 4; ++r) {
      const int i = q0 + qg * 16 + kg * 4 + r;
      atomicAdd(Oat + (size_t)i * 128 + h * 32 + li,      acc[qg][0][r]);
      atomicAdd(Oat + (size_t)i * 128 + h * 32 + 16 + li, acc[qg][1][r]);
    }
    float sd = sden[qg];
    sd += __shfl_xor(sd, 16);
    sd += __shfl_xor(sd, 32);
    if (lane < 16) atomicAdd(denom + (size_t)h * 4096 + q0 + qg * 16 + li, sd);
  }
}

// ---------------------------------------------------------------------------
// K3: out = (Oat/denom) @ w_out^T + b_out  (M=4096, K=128, N=128)
// grid (256 Mtiles of 16, 2 N-halves), 256 thr = 4 waves, one 16-col tile per
// wave (A re-loads hit L1).
// ---------------------------------------------------------------------------
__global__ __launch_bounds__(256) void proj_kernel(
    const float* __restrict__ Oat, const float* __restrict__ denom,
    const float* __restrict__ w_out, const float* __restrict__ b_out,
    float* __restrict__ out) {
  const int tid = threadIdx.x;
  const int w = tid >> 6, lane = tid & 63, li = lane & 15, kg = lane >> 4;
  const int i0 = blockIdx.x * 16;
  const int n0 = blockIdx.y * 64;
  const int i = i0 + li;

  s16x8 ao[4];
#pragma unroll
  for (int kc = 0; kc < 4; ++kc) {
    const float inv = 1.f / denom[(size_t)kc * 4096 + i];
    const f32x4* p = (const f32x4*)(Oat + (size_t)i * 128 + kc * 32 + kg * 8);
    f32x4 a = p[0], b = p[1];
    s16x8 r;
    r[0]=(short)f2bf(a[0]*inv); r[1]=(short)f2bf(a[1]*inv);
    r[2]=(short)f2bf(a[2]*inv); r[3]=(short)f2bf(a[3]*inv);
    r[4]=(short)f2bf(b[0]*inv); r[5]=(short)f2bf(b[1]*inv);
    r[6]=(short)f2bf(b[2]*inv); r[7]=(short)f2bf(b[3]*inv);
    ao[kc] = r;
  }
  const int c = n0 + w * 16 + li;
  f32x4 acc = {0, 0, 0, 0};
#pragma unroll
  for (int kc = 0; kc < 4; ++kc) {
    s16x8 bw = load8f_bf16(w_out + (size_t)c * 128 + kc * 32 + kg * 8);
    acc = __builtin_amdgcn_mfma_f32_16x16x32_bf16(ao[kc], bw, acc, 0, 0, 0);
  }
  const float bias = b_out[c];
#pragma unroll
  for (int r = 0; r < 4; ++r)
    out[(size_t)(i0 + kg * 4 + r) * 128 + c] = acc[r] + bias;
}

// ---------------------------------------------------------------------------
extern "C" void kernel_launch(void* const* d_in, const int* in_sizes, int n_in,
                              void* d_out, int out_size, void* d_ws, size_t ws_size,
                              hipStream_t stream) {
  const float* x     = (const float*)d_in[0];
  const float* w_in  = (const float*)d_in[1];
  const float* w_out = (const float*)d_in[2];
  const float* b_out = (const float*)d_in[3];
  float* out = (float*)d_out;

  char* ws = (char*)d_ws;
  float* Oat     = (float*)ws;                          // [4096][128] f32 (2MB)
  float* denom   = (float*)(ws + 2097152);              // [4][4096] f32 (64KB)
  float* part_sq = (float*)(ws + 2097152 + 65536);      // [256][128] f32 (128KB)
  u16*   Qb  = (u16*)(ws + 2097152 + 65536 + 131072);               // [4][4096][32]
  u16*   Kb  = (u16*)(ws + 2097152 + 65536 + 131072 + 1048576);     // [4][4096][32]
  u16*   Vtb = (u16*)(ws + 2097152 + 65536 + 131072 + 2 * 1048576); // [4][32][4096]

  // qkv zeroes Oat+denom internally (135168 f32x4 from ws base)
  qkv_kernel <<<dim3(128, 3),   256, 0, stream>>>(x, w_in, Qb, Kb, Vtb, part_sq, Oat);
  attn_kernel<<<dim3(64, 4, 4), 256, 0, stream>>>(Qb, Kb, Vtb, part_sq, Oat, denom);
  proj_kernel<<<dim3(256, 2),   256, 0, stream>>>(Oat, denom, w_out, b_out, out);
}

// Round 9
// 102.248 us; speedup vs baseline: 1.3037x; 1.3037x over previous
//
#include <hip/hip_runtime.h>
#include <hip/hip_bf16.h>

// Attention_6828998000803 on MI355X (gfx950)
// H=W=64, C=128, HEADS=4, DIM_HEAD=32, HW=4096, SCALE=10, EPS=1e-8
//
// qkv GEMM (writes Q,K,V^T bf16 + per-block sumsq partials)
// -> flash attention: block = (64 q-rows, head), 1024 thr = 16 waves
//    (4 wq x 4 wk).  256-key tiles double-buffered in LDS (staged ONCE,
//    shared by all 16 waves), linear softmax (|sim|<=~1.3), LDS partial
//    combine, ZERO atomics, plain stores.
// -> output projection (divide by denom, bf16 MFMA, + bias)

typedef float  f32x4 __attribute__((ext_vector_type(4)));
typedef short  s16x8 __attribute__((ext_vector_type(8)));
typedef unsigned short u16x4 __attribute__((ext_vector_type(4)));
typedef unsigned short u16;

__device__ __forceinline__ u16 f2bf(float f) {
  unsigned int u = __float_as_uint(f);
  u += 0x7FFFu + ((u >> 16) & 1u);   // round-to-nearest-even
  return (u16)(u >> 16);
}
__device__ __forceinline__ float bf2f(u16 u) {
  return __uint_as_float(((unsigned int)u) << 16);
}
__device__ __forceinline__ s16x8 load8f_bf16(const float* p) {
  const f32x4* q = (const f32x4*)p;
  f32x4 a = q[0], b = q[1];
  s16x8 r;
  r[0]=(short)f2bf(a[0]); r[1]=(short)f2bf(a[1]); r[2]=(short)f2bf(a[2]); r[3]=(short)f2bf(a[3]);
  r[4]=(short)f2bf(b[0]); r[5]=(short)f2bf(b[1]); r[6]=(short)f2bf(b[2]); r[7]=(short)f2bf(b[3]);
  return r;
}

// ---------------------------------------------------------------------------
// K1: qkv = x @ w_in^T  (M=4096, K=128, N=384), grid (128 Mtiles of 32, 3 g)
// 256 thr = 4 waves: wave (wm,wn) does rows wm*16..+16, cols wn*64..+64.
// ---------------------------------------------------------------------------
__global__ __launch_bounds__(256) void qkv_kernel(
    const float* __restrict__ x, const float* __restrict__ w_in,
    u16* __restrict__ Qb, u16* __restrict__ Kb, u16* __restrict__ Vtb,
    float* __restrict__ part_sq) {
  __shared__ float sqpart[2][128];
  const int tid = threadIdx.x;
  const int w = tid >> 6, lane = tid & 63, li = lane & 15, kg = lane >> 4;
  const int wm = w & 1, wn = w >> 1;
  const int g = blockIdx.y;
  const int mb = blockIdx.x;
  const int irow = mb * 32 + wm * 16;

  s16x8 ax[4];
#pragma unroll
  for (int kc = 0; kc < 4; ++kc)
    ax[kc] = load8f_bf16(x + (size_t)(irow + li) * 128 + kc * 32 + kg * 8);

  const float* W = w_in + (size_t)g * 128 * 128;
#pragma unroll
  for (int nt = 0; nt < 4; ++nt) {
    const int colrel = wn * 64 + nt * 16 + li;
    f32x4 acc = {0.f, 0.f, 0.f, 0.f};
#pragma unroll
    for (int kc = 0; kc < 4; ++kc) {
      s16x8 bw = load8f_bf16(W + (size_t)colrel * 128 + kc * 32 + kg * 8);
      acc = __builtin_amdgcn_mfma_f32_16x16x32_bf16(ax[kc], bw, acc, 0, 0, 0);
    }
    const int h = colrel >> 5, d = colrel & 31;
    const int r0 = irow + kg * 4;
    if (g == 2) {
      u16x4 pv;
#pragma unroll
      for (int r = 0; r < 4; ++r) pv[r] = f2bf(acc[r]);
      *(u16x4*)(Vtb + ((size_t)(h * 32 + d) * 4096 + r0)) = pv;   // V^T[h][d][i]
    } else {
      float ss = acc[0]*acc[0] + acc[1]*acc[1] + acc[2]*acc[2] + acc[3]*acc[3];
      ss += __shfl_xor(ss, 16);
      ss += __shfl_xor(ss, 32);            // sum over this wave's 16 rows
      if (lane < 16) sqpart[wm][colrel] = ss;
      u16* dst = (g == 0 ? Qb : Kb);
#pragma unroll
      for (int r = 0; r < 4; ++r)
        dst[((size_t)h * 4096 + r0 + r) * 32 + d] = f2bf(acc[r]);
    }
  }
  __syncthreads();
  if (g < 2 && tid < 128)
    part_sq[((size_t)g * 128 + tid) * 128 + mb] = sqpart[0][tid] + sqpart[1][tid];
}

// ---------------------------------------------------------------------------
// K2: flash attention, linear softmax.  grid (64 q-blocks, 4 heads) = 256
// blocks (1/CU), 1024 thr = 16 waves = (wq 0..3) x (wk 0..3).
// Wave (wq,wk): q-rows q0+wq*16+[0,16) x keys (per 256-key staged tile)
// wk*64+[0,64).  K/V staged ONCE per tile into double-buffered swizzled LDS
// (T14: global->reg before compute, ds_write after barrier).  Partial O and
// denom combined via LDS at the end; plain global stores, no atomics.
// LDS map (bytes): [0,32K) Kbuf[2][256][64B]swz (later comb[16][16][32]f32)
//                  [32K,64K) Vbuf[2][32][512B]swz
//                  [64K,96K) P[16 waves][16][128B]swz
//                  [96K..) dl[16][16]f32, scs[32]f32
// ---------------------------------------------------------------------------
__global__ __launch_bounds__(1024, 4) void attn_kernel(
    const u16* __restrict__ Qb, const u16* __restrict__ Kb,
    const u16* __restrict__ Vtb, const float* __restrict__ part_sq,
    float* __restrict__ Oat, float* __restrict__ denom) {
  __shared__ __align__(16) char lds[99456];
  const int tid = threadIdx.x;
  const int w = tid >> 6, lane = tid & 63, li = lane & 15, kg = lane >> 4;
  const int wq = w >> 2, wk = w & 3;
  const int h = blockIdx.y, q0 = blockIdx.x * 64;
  float* dl  = (float*)(lds + 98304);
  float* scs = (float*)(lds + 99328);
  const u16* Kh = Kb  + (size_t)h * 4096 * 32;
  const u16* Vh = Vtb + (size_t)h * 32 * 4096;
  const int jl = tid >> 2, sl = tid & 3;     // K staging coords (16B granules)
  const int dv = tid >> 5, sv = tid & 31;    // V staging coords

  // ---- stage tile 0 (keys [0,256))
  {
    s16x8 kreg = *(const s16x8*)(Kh + (size_t)jl * 32 + sl * 8);
    s16x8 vreg = *(const s16x8*)(Vh + (size_t)dv * 4096 + sv * 8);
    *(s16x8*)(lds + jl * 64 + ((sl * 16) ^ ((jl & 7) << 4))) = kreg;
    *(s16x8*)(lds + 32768 + dv * 512 + ((sv * 16) ^ ((dv & 7) << 4))) = vreg;
  }
  // ---- scale table (wave 0): 10/(||q_d|| * ||k_d||)
  if (w == 0) {
    const int kind = lane >> 5, d = lane & 31;
    const f32x4* p4 = (const f32x4*)(part_sq + (size_t)(kind * 128 + h * 32 + d) * 128);
    float sum = 0.f;
#pragma unroll
    for (int m = 0; m < 32; ++m) { f32x4 v = p4[m]; sum += (v[0]+v[1]) + (v[2]+v[3]); }
    float n = fmaxf(sqrtf(sum), 1e-8f);
    float other = __shfl_xor(n, 32);
    if (lane < 32) scs[lane] = 10.f / (n * other);
  }
  __syncthreads();

  // ---- Q fragment (rows q0+wq*16+[0,16)), scale folded in
  s16x8 aq;
  {
    const u16* qp = Qb + ((size_t)h * 4096 + q0 + wq * 16 + li) * 32 + kg * 8;
    s16x8 qr = *(const s16x8*)qp;
#pragma unroll
    for (int e = 0; e < 8; ++e) aq[e] = (short)f2bf(bf2f((u16)qr[e]) * scs[kg * 8 + e]);
  }

  f32x4 acc0 = {0,0,0,0}, acc1 = {0,0,0,0};
  float sden = 0.f;
  const int psw  = (li & 7) << 4;
  char* Pslab = lds + 65536 + w * 2048 + li * 128;
  const int kswz = (kg * 16) ^ psw;

  int cur = 0;
  for (int jt = 0; jt < 16; ++jt) {
    // prefetch next tile into regs (lands during compute below)
    s16x8 kreg = {}, vreg = {};
    if (jt < 15) {
      const int j0n = (jt + 1) * 256;
      kreg = *(const s16x8*)(Kh + (size_t)(j0n + jl) * 32 + sl * 8);
      vreg = *(const s16x8*)(Vh + (size_t)dv * 4096 + j0n + sv * 8);
    }
    const char* Kc = lds + cur * 16384;
    const char* Vc = lds + 32768 + cur * 16384;
    // S^T = K Q^T over this wave's 64-key quarter: lane holds S[j][q=li]
    f32x4 st[4];
#pragma unroll
    for (int jb = 0; jb < 4; ++jb) {
      s16x8 kf = *(const s16x8*)(Kc + (wk * 64 + jb * 16 + li) * 64 + kswz);
      f32x4 z = {0, 0, 0, 0};
      st[jb] = __builtin_amdgcn_mfma_f32_16x16x32_bf16(kf, aq, z, 0, 0, 0);
    }
    // exp (no max), denom accumulate, pack P -> per-wave LDS slab
#pragma unroll
    for (int jb = 0; jb < 4; ++jb) {
      float p0 = __expf(st[jb][0]), p1 = __expf(st[jb][1]);
      float p2 = __expf(st[jb][2]), p3 = __expf(st[jb][3]);
      sden += (p0 + p1) + (p2 + p3);
      uint2 pk;
      pk.x = (unsigned)f2bf(p0) | ((unsigned)f2bf(p1) << 16);
      pk.y = (unsigned)f2bf(p2) | ((unsigned)f2bf(p3) << 16);
      *(uint2*)(Pslab + ((jb * 32 + kg * 8) ^ psw)) = pk;
    }
    // O += P V  (wave-internal P round-trip; V from shared staged tile)
#pragma unroll
    for (int c = 0; c < 2; ++c) {
      s16x8 ap = *(const s16x8*)(Pslab + ((c * 64 + kg * 16) ^ psw));
      const int vsw = ((wk * 8 + c * 4 + kg) * 16) ^ psw;
      s16x8 vf0 = *(const s16x8*)(Vc + li * 512 + vsw);
      s16x8 vf1 = *(const s16x8*)(Vc + (li + 16) * 512 + vsw);
      acc0 = __builtin_amdgcn_mfma_f32_16x16x32_bf16(ap, vf0, acc0, 0, 0, 0);
      acc1 = __builtin_amdgcn_mfma_f32_16x16x32_bf16(ap, vf1, acc1, 0, 0, 0);
    }
    __syncthreads();
    if (jt < 15) {
      char* Kn = lds + (cur ^ 1) * 16384;
      char* Vn = lds + 32768 + (cur ^ 1) * 16384;
      *(s16x8*)(Kn + jl * 64 + ((sl * 16) ^ ((jl & 7) << 4))) = kreg;
      *(s16x8*)(Vn + dv * 512 + ((sv * 16) ^ ((dv & 7) << 4))) = vreg;
    }
    __syncthreads();
    cur ^= 1;
  }

  // ---- combine partials across wk via LDS (no atomics)
  sden += __shfl_xor(sden, 16);
  sden += __shfl_xor(sden, 32);            // denom for q-row li over this stripe
  if (lane < 16) dl[w * 16 + li] = sden;
  float* comb = (float*)lds;               // overlays Kbuf (done with it)
#pragma unroll
  for (int r = 0; r < 4; ++r) {
    comb[(w * 16 + kg * 4 + r) * 32 + li]      = acc0[r];
    comb[(w * 16 + kg * 4 + r) * 32 + 16 + li] = acc1[r];
  }
  __syncthreads();
  {
    const int row = tid >> 4, cp = (tid & 15) * 2;
    const int wb = (row >> 4) * 4, r16 = row & 15;
    float o0 = 0.f, o1 = 0.f;
#pragma unroll
    for (int k2 = 0; k2 < 4; ++k2) {
      const float* src = comb + ((wb + k2) * 16 + r16) * 32 + cp;
      o0 += src[0]; o1 += src[1];
    }
    float2 o2 = {o0, o1};
    *(float2*)(Oat + (size_t)(q0 + row) * 128 + h * 32 + cp) = o2;
    if (tid < 64) {
      float ds = 0.f;
#pragma unroll
      for (int k2 = 0; k2 < 4; ++k2) ds += dl[((tid >> 4) * 4 + k2) * 16 + (tid & 15)];
      denom[(size_t)h * 4096 + q0 + tid] = ds;
    }
  }
}

// ---------------------------------------------------------------------------
// K3: out = (Oat/denom) @ w_out^T + b_out  (M=4096, K=128, N=128)
// grid (256 Mtiles of 16, 2 N-halves), 256 thr = 4 waves.
// ---------------------------------------------------------------------------
__global__ __launch_bounds__(256) void proj_kernel(
    const float* __restrict__ Oat, const float* __restrict__ denom,
    const float* __restrict__ w_out, const float* __restrict__ b_out,
    float* __restrict__ out) {
  const int tid = threadIdx.x;
  const int w = tid >> 6, lane = tid & 63, li = lane & 15, kg = lane >> 4;
  const int i0 = blockIdx.x * 16;
  const int n0 = blockIdx.y * 64;
  const int i = i0 + li;

  s16x8 ao[4];
#pragma unroll
  for (int kc = 0; kc < 4; ++kc) {
    const float inv = 1.f / denom[(size_t)kc * 4096 + i];
    const f32x4* p = (const f32x4*)(Oat + (size_t)i * 128 + kc * 32 + kg * 8);
    f32x4 a = p[0], b = p[1];
    s16x8 r;
    r[0]=(short)f2bf(a[0]*inv); r[1]=(short)f2bf(a[1]*inv);
    r[2]=(short)f2bf(a[2]*inv); r[3]=(short)f2bf(a[3]*inv);
    r[4]=(short)f2bf(b[0]*inv); r[5]=(short)f2bf(b[1]*inv);
    r[6]=(short)f2bf(b[2]*inv); r[7]=(short)f2bf(b[3]*inv);
    ao[kc] = r;
  }
  const int c = n0 + w * 16 + li;
  f32x4 acc = {0, 0, 0, 0};
#pragma unroll
  for (int kc = 0; kc < 4; ++kc) {
    s16x8 bw = load8f_bf16(w_out + (size_t)c * 128 + kc * 32 + kg * 8);
    acc = __builtin_amdgcn_mfma_f32_16x16x32_bf16(ao[kc], bw, acc, 0, 0, 0);
  }
  const float bias = b_out[c];
#pragma unroll
  for (int r = 0; r < 4; ++r)
    out[(size_t)(i0 + kg * 4 + r) * 128 + c] = acc[r] + bias;
}

// ---------------------------------------------------------------------------
extern "C" void kernel_launch(void* const* d_in, const int* in_sizes, int n_in,
                              void* d_out, int out_size, void* d_ws, size_t ws_size,
                              hipStream_t stream) {
  const float* x     = (const float*)d_in[0];
  const float* w_in  = (const float*)d_in[1];
  const float* w_out = (const float*)d_in[2];
  const float* b_out = (const float*)d_in[3];
  float* out = (float*)d_out;

  char* ws = (char*)d_ws;
  float* Oat     = (float*)ws;                          // [4096][128] f32 (2MB)
  float* denom   = (float*)(ws + 2097152);              // [4][4096] f32 (64KB)
  float* part_sq = (float*)(ws + 2097152 + 65536);      // [256][128] f32 (128KB)
  u16*   Qb  = (u16*)(ws + 2097152 + 65536 + 131072);               // [4][4096][32]
  u16*   Kb  = (u16*)(ws + 2097152 + 65536 + 131072 + 1048576);     // [4][4096][32]
  u16*   Vtb = (u16*)(ws + 2097152 + 65536 + 131072 + 2 * 1048576); // [4][32][4096]

  qkv_kernel <<<dim3(128, 3), 256,  0, stream>>>(x, w_in, Qb, Kb, Vtb, part_sq);
  attn_kernel<<<dim3(64, 4),  1024, 0, stream>>>(Qb, Kb, Vtb, part_sq, Oat, denom);
  proj_kernel<<<dim3(256, 2), 256,  0, stream>>>(Oat, denom, w_out, b_out, out);
}